// Round 5
// baseline (4973.542 us; speedup 1.0000x reference)
//
#include <hip/hip_runtime.h>
#include <hip/hip_bf16.h>

// ---------------- problem constants ----------------
constexpr int N_NODE = 4096;
constexpr int DIM    = 512;
constexpr int HID    = 256;
constexpr int NCLS   = 32;
constexpr int N_EDGE = 131072;
constexpr float ALPHA_C = 0.85f;
constexpr float EPS_C   = 1e-8f;
constexpr int N_ITER = 46;      // Jacobi apps; err <= 0.85^46 * ~4.6 ~= 2.6e-3
constexpr int ELLW   = 12;      // ELL width; degree tail goes to COO overflow

// ---------------- workspace layout (bytes) ----------------
// zeroed region (by mlp_kernel threads): [0, ZERO_BYTES)
constexpr size_t OFF_BITMAP  = 0x000000;  // 2 MB dedup bitmap
constexpr size_t OFF_ELLRAW  = 0x200000;  // 192 KB raw ELL (uint, [slot][row])
constexpr size_t OFF_ROWCNT  = 0x230000;  // 16 KB per-row nnz count (== degree)
constexpr size_t OFF_DIAGEX  = 0x234000;  // 16 KB self-loop exists
constexpr size_t OFF_CNT     = 0x238000;  // [0] = overflow count
constexpr size_t ZERO_BYTES  = 0x239000;  // 145664 uint4 stores
// non-zeroed
constexpr size_t OFF_LOGITS  = 0x240000;  // 512 KB
constexpr size_t OFF_F       = 0x2C0000;  // 512 KB normalized logits
constexpr size_t OFF_DIAGSIM = 0x340000;  // 16 KB
constexpr size_t OFF_OCOO    = 0x344000;  // 1 MB raw overflow {rc, simbits}

// ---------------- K1: zero workspace + MLP (fp32) ----------------
// fp32 mandatory: bf16 flips sims across the 0.1 threshold -> wrong S rows.
// Identical math to the R3/R4 passing versions.
__global__ __launch_bounds__(512) void mlp_kernel(
    const float* __restrict__ attr, const float* __restrict__ W0,
    const float* __restrict__ b0, const float* __restrict__ W1,
    const float* __restrict__ b1, float* __restrict__ logits,
    float* __restrict__ f, uint4* __restrict__ zbase)
{
    const int t = threadIdx.x;
    const int b = blockIdx.x;
    // zero phase: 512*512 threads cover ZERO_BYTES in one uint4 store each.
    // Consumed only by LATER kernels (edge/solve) -> kernel-boundary safe (G16).
    {
        const int g = b * 512 + t;
        if (g < (int)(ZERO_BYTES / 16)) zbase[g] = make_uint4(0u, 0u, 0u, 0u);
    }

    __shared__ __align__(16) float attr_s[8 * DIM];   // 16 KB
    __shared__ __align__(16) float x_s[8 * HID];      // 8 KB
    const int node0 = b * 8;
    const float* ap = attr + (size_t)node0 * DIM;
    for (int i = t; i < 8 * DIM / 4; i += 512)
        ((float4*)attr_s)[i] = ((const float4*)ap)[i];
    __syncthreads();

    // hidden: 4 node-groups x 128 threads; thread = 2 hidden units x 2 nodes
    const int pg = t >> 7;               // node-group 0..3 (2 nodes each)
    const int hh = (t & 127) * 2;        // hidden pair base
    const float2 b0v = *(const float2*)(b0 + hh);
    float acc0[2], acc1[2];
#pragma unroll
    for (int n = 0; n < 2; n++) { acc0[n] = b0v.x; acc1[n] = b0v.y; }

    for (int k = 0; k < DIM; k += 4) {
        const float2 w0 = *(const float2*)(W0 + (k + 0) * HID + hh);
        const float2 w1 = *(const float2*)(W0 + (k + 1) * HID + hh);
        const float2 w2 = *(const float2*)(W0 + (k + 2) * HID + hh);
        const float2 w3 = *(const float2*)(W0 + (k + 3) * HID + hh);
#pragma unroll
        for (int n = 0; n < 2; n++) {
            const float4 a = *(const float4*)(attr_s + (2 * pg + n) * DIM + k);
            acc0[n] = fmaf(a.x, w0.x, acc0[n]); acc1[n] = fmaf(a.x, w0.y, acc1[n]);
            acc0[n] = fmaf(a.y, w1.x, acc0[n]); acc1[n] = fmaf(a.y, w1.y, acc1[n]);
            acc0[n] = fmaf(a.z, w2.x, acc0[n]); acc1[n] = fmaf(a.z, w2.y, acc1[n]);
            acc0[n] = fmaf(a.w, w3.x, acc0[n]); acc1[n] = fmaf(a.w, w3.y, acc1[n]);
        }
    }
#pragma unroll
    for (int n = 0; n < 2; n++) {
        x_s[(2 * pg + n) * HID + hh]     = fmaxf(acc0[n], 0.0f);
        x_s[(2 * pg + n) * HID + hh + 1] = fmaxf(acc1[n], 0.0f);
    }
    __syncthreads();

    if (t < 256) {
        const int n = t >> 5, c = t & 31;
        float lg = b1[c];
        for (int k = 0; k < HID; k += 4) {
            const float4 x4 = *(const float4*)(x_s + n * HID + k);
            lg = fmaf(x4.x, W1[(k + 0) * NCLS + c], lg);
            lg = fmaf(x4.y, W1[(k + 1) * NCLS + c], lg);
            lg = fmaf(x4.z, W1[(k + 2) * NCLS + c], lg);
            lg = fmaf(x4.w, W1[(k + 3) * NCLS + c], lg);
        }
        float sq = lg * lg;
#pragma unroll
        for (int m = 16; m >= 1; m >>= 1) sq += __shfl_xor(sq, m, 32);
        const float nr = fmaxf(sqrtf(sq), EPS_C);
        const int r = node0 + n;
        logits[r * NCLS + c] = lg;
        f[r * NCLS + c] = lg / nr;
    }
}

// ---------------- K2: edge sims + dedup -> raw ELL + raw COO overflow ----------
// col packed in low 12 mantissa bits of the fp32 sim (rel err 2^-12 -> ~1e-3 out).
__global__ __launch_bounds__(256) void edge_kernel(
    const int* __restrict__ row, const int* __restrict__ col,
    const float* __restrict__ f, unsigned int* __restrict__ bitmap,
    int* __restrict__ row_count, unsigned int* __restrict__ ell_raw,
    int2* __restrict__ ocoo, float* __restrict__ diag_sim,
    int* __restrict__ diag_ex, int* __restrict__ ocnt)
{
    const int e = blockIdx.x * blockDim.x + threadIdx.x;
    const int r = row[e], c = col[e];
    const float4* fr = (const float4*)(f + r * NCLS);
    const float4* fc = (const float4*)(f + c * NCLS);
    float sim = 0.f;
#pragma unroll
    for (int q = 0; q < 8; q++) {
        float4 a = fr[q], b = fc[q];
        sim += a.x * b.x + a.y * b.y + a.z * b.z + a.w * b.w;
    }
    if (sim < 0.1f) return;  // where(sim<0.1, 0, sim): zero == absent cell
    if (r == c) {
        diag_ex[r] = 1;                  // dup writes identical
        diag_sim[r] = sim;
    } else {
        // dedup: .at[r,c].set counts a cell ONCE even with duplicate edges
        unsigned int bit = (unsigned int)r * N_NODE + (unsigned int)c;
        unsigned int w = bit >> 5, m = 1u << (bit & 31);
        unsigned int old = atomicOr(&bitmap[w], m);
        if (!(old & m)) {
            int pos = atomicAdd(&row_count[r], 1);
            if (pos < ELLW) {
                unsigned int u = (__float_as_uint(sim) & ~0xFFFu) | (unsigned int)c;
                ell_raw[pos * N_NODE + r] = u;   // [slot][row]: lane-coalesced
            } else {
                int o = atomicAdd(ocnt, 1);
                ocoo[o] = make_int2((r << 12) | c, __float_as_int(sim));
            }
        }
    }
}

// ---------------- K3: block-local transform + register-ELL Jacobi solve -------
// Block cb owns column cb (the iteration never mixes columns). The normalize/exp
// transform is computed REDUNDANTLY per block but kept entirely in registers/LDS
// -- no same-kernel global write->read (that was R4's cross-XCD staleness bug).
// Hot loop: per thread 4 rows x 12 slots, everything in regs + LDS. Only global
// ops per iteration: the small raw-COO overflow read (written by edge_kernel,
// kernel-boundary safe) with its transform recomputed from LDS denom/inv.
__global__ __launch_bounds__(1024) void solve_kernel(
    const float* __restrict__ logits, const unsigned int* __restrict__ ell_raw,
    const int2* __restrict__ ocoo, const int* __restrict__ cnt,
    const int* __restrict__ row_count, const int* __restrict__ diag_ex,
    const float* __restrict__ diag_sim, float* __restrict__ out)
{
    __shared__ float Ya[N_NODE];    // 16 KB Y buffer
    __shared__ float Yb[N_NODE];    // 16 KB Y buffer; prologue: overflow-exp acc
    __shared__ float tDen[N_NODE];  // 16 KB denom (rowsum); prologue: ovf rowsum
    __shared__ float tInv[N_NODE];  // 16 KB 1/degA
    // 64 KB total

    const int t  = threadIdx.x;
    const int cb = blockIdx.x;
    const int no = cnt[0];

    const float S00 = diag_ex[0] ? diag_sim[0] : 0.0f;
    const int rm  = (S00 == 1.0f) ? 1 : 0;                // remove diagonal?
    const int add = ((rm ? 0.0f : S00) == 0.0f) ? 1 : 0;  // add diag(lam)?

    // --- prologue A: zero scratch; raw overflow row-sum contributions ---
#pragma unroll
    for (int q = 0; q < 4; q++) { int r = t + q * 1024; tDen[r] = 0.0f; Yb[r] = 0.0f; }
    __syncthreads();
    for (int i = t; i < no; i += 1024) {
        int2 u = ocoo[i];
        atomicAdd(&tDen[u.x >> 12], __int_as_float(u.y));
    }
    __syncthreads();

    // --- prologue B: load ELL into registers; row sums -> denom ---
    unsigned int ellreg[4][ELLW];     // 48 VGPRs, live through all iterations
#pragma unroll
    for (int q = 0; q < 4; q++) {
        const int r = t + q * 1024;
        float ssum = 0.0f;
#pragma unroll
        for (int s = 0; s < ELLW; s++) {
            unsigned int u = ell_raw[s * N_NODE + r];   // coalesced dword
            ellreg[q][s] = u;
            ssum += __uint_as_float(u & ~0xFFFu);       // padding u=0 adds 0
        }
        const float d = diag_ex[r] ? diag_sim[r] : 0.0f;
        const float d_eff = rm ? 0.0f : d;
        const float rowsum = d_eff + ssum + tDen[r];    // all vals >= 0.1 > 0
        // benign same-value race note: tDen written only by this thread below
        __syncthreads();  // ensure all tDen(ovf) reads done before overwrite
        tDen[r] = (rowsum == 0.0f) ? 1.0f : rowsum;
        __syncthreads();
    }

    // --- prologue C: overflow exp contributions (into Yb) ---
    for (int i = t; i < no; i += 1024) {
        int2 u = ocoo[i]; int r = u.x >> 12;
        atomicAdd(&Yb[r], expf(__int_as_float(u.y) / tDen[r]));
    }
    __syncthreads();

    // --- prologue D: degA, inv, pdiag; transform ELL in registers; init Y0 ---
    float base[4], pd[4];
#pragma unroll
    for (int q = 0; q < 4; q++) {
        const int r = t + q * 1024;
        const float denom = tDen[r];
        float esum = 0.0f;
#pragma unroll
        for (int s = 0; s < ELLW; s++) {
            unsigned int u = ellreg[q][s];
            float v = __uint_as_float(u & ~0xFFFu);
            esum += u ? expf(v / denom) : 0.0f;         // exp only on nz pattern
        }
        const float d = diag_ex[r] ? diag_sim[r] : 0.0f;
        const float d_eff = rm ? 0.0f : d;
        const float sn_d = d_eff / denom;
        const int degree = row_count[r] + ((sn_d != 0.0f) ? 1 : 0);
        const float lam = 1.0f / (float)(degree + 1);
        const float diagf = sn_d + (add ? lam : 0.0f);
        const float a_d = (diagf != 0.0f) ? expf(diagf) : 0.0f;
        const float degA = a_d + esum + Yb[r];
        const float inv = 1.0f / fmaxf(degA, EPS_C);
        tInv[r] = inv;
        pd[q] = ALPHA_C * a_d * inv;
#pragma unroll
        for (int s = 0; s < ELLW; s++) {
            unsigned int u = ellreg[q][s], outu = 0u;
            if (u) {
                float v = __uint_as_float(u & ~0xFFFu);
                float tv = ALPHA_C * expf(v / denom) * inv;
                outu = (__float_as_uint(tv) & ~0xFFFu) | (u & 0xFFFu);
            }
            ellreg[q][s] = outu;                         // stays in registers
        }
        base[q] = (1.0f - ALPHA_C) * logits[r * NCLS + cb];
        Ya[r] = base[q];                                 // Y0 = (1-a)L
    }
    __syncthreads();

    // --- 46x Jacobi: Y <- base + pd*Y + reg-ELL LDS gather + on-the-fly ovf ---
    float* src = Ya;
    float* dst = Yb;
    for (int it = 0; it < N_ITER; ++it) {
#pragma unroll
        for (int q = 0; q < 4; q++) {
            const int r = t + q * 1024;
            float acc = fmaf(pd[q], src[r], base[q]);
#pragma unroll
            for (int s = 0; s < ELLW; s++) {
                unsigned int u = ellreg[q][s];
                acc = fmaf(__uint_as_float(u & ~0xFFFu), src[u & 0xFFFu], acc);
            }
            dst[r] = acc;
        }
        __syncthreads();
        for (int i = t; i < no; i += 1024) {             // small tail, L2-hot
            int2 u = ocoo[i]; int rr = u.x >> 12;
            float tv = ALPHA_C * expf(__int_as_float(u.y) / tDen[rr]) * tInv[rr];
            atomicAdd(&dst[rr], tv * src[u.x & 0xFFF]);
        }
        __syncthreads();
        float* tmp = src; src = dst; dst = tmp;
    }

#pragma unroll
    for (int q = 0; q < 4; q++) {
        const int r = t + q * 1024;
        out[r * NCLS + cb] = src[r];
    }
}

// ---------------- launch: 3 graph nodes ----------------
extern "C" void kernel_launch(void* const* d_in, const int* in_sizes, int n_in,
                              void* d_out, int out_size, void* d_ws, size_t ws_size,
                              hipStream_t stream)
{
    const float* attr = (const float*)d_in[0];
    const int*   row  = (const int*)d_in[1];
    const int*   col  = (const int*)d_in[2];
    const float* W0   = (const float*)d_in[3];
    const float* b0   = (const float*)d_in[4];
    const float* W1   = (const float*)d_in[5];
    const float* b1   = (const float*)d_in[6];
    float* out = (float*)d_out;

    char* ws = (char*)d_ws;
    unsigned int* bitmap  = (unsigned int*)(ws + OFF_BITMAP);
    unsigned int* ell_raw = (unsigned int*)(ws + OFF_ELLRAW);
    int*   row_count = (int*)(ws + OFF_ROWCNT);
    int*   diag_ex   = (int*)(ws + OFF_DIAGEX);
    int*   cnt       = (int*)(ws + OFF_CNT);
    float* logits    = (float*)(ws + OFF_LOGITS);
    float* f         = (float*)(ws + OFF_F);
    float* diag_sim  = (float*)(ws + OFF_DIAGSIM);
    int2*  ocoo      = (int2*)(ws + OFF_OCOO);

    mlp_kernel<<<N_NODE / 8, 512, 0, stream>>>(attr, W0, b0, W1, b1, logits, f,
                                               (uint4*)ws);
    edge_kernel<<<N_EDGE / 256, 256, 0, stream>>>(row, col, f, bitmap, row_count,
                                                  ell_raw, ocoo, diag_sim,
                                                  diag_ex, cnt);
    solve_kernel<<<NCLS, 1024, 0, stream>>>(logits, ell_raw, ocoo, cnt,
                                            row_count, diag_ex, diag_sim, out);
}

// Round 6
// 2591.388 us; speedup vs baseline: 1.9193x; 1.9193x over previous
//
#include <hip/hip_runtime.h>
#include <hip/hip_bf16.h>

// ---------------- problem constants ----------------
constexpr int N_NODE = 4096;
constexpr int DIM    = 512;
constexpr int HID    = 256;
constexpr int NCLS   = 32;
constexpr int N_EDGE = 131072;
constexpr float ALPHA_C = 0.85f;
constexpr float EPS_C   = 1e-8f;
constexpr int N_ITER = 22;      // Jacobi sweeps, then Perron extrapolation:
                                // Y* ~= Y_K + (Y_K - Y_{K-1}) * a/(1-a)  (M*1 = a*1 exact)
constexpr float EXTRAP = ALPHA_C / (1.0f - ALPHA_C);   // 5.666667
constexpr int ELLW   = 12;      // ELL width; degree tail goes to COO overflow

// ---------------- workspace layout (bytes) ----------------
// zeroed region (by mlp_kernel threads): [0, ZERO_BYTES)
constexpr size_t OFF_BITMAP  = 0x000000;  // 2 MB dedup bitmap
constexpr size_t OFF_ELLRAW  = 0x200000;  // 192 KB raw ELL (uint, [slot][row])
constexpr size_t OFF_ROWCNT  = 0x230000;  // 16 KB per-row nnz count (== degree)
constexpr size_t OFF_DIAGEX  = 0x234000;  // 16 KB self-loop exists
constexpr size_t OFF_CNT     = 0x238000;  // [0] = overflow count
constexpr size_t ZERO_BYTES  = 0x239000;  // 145664 uint4 stores
// non-zeroed
constexpr size_t OFF_LOGITS  = 0x240000;  // 512 KB
constexpr size_t OFF_F       = 0x2C0000;  // 512 KB normalized logits
constexpr size_t OFF_DIAGSIM = 0x340000;  // 16 KB
constexpr size_t OFF_OCOO    = 0x344000;  // 1 MB raw overflow {rc, simbits}

// ---------------- K1: zero workspace + MLP (fp32) ----------------
// fp32 mandatory: bf16 flips sims across the 0.1 threshold -> wrong S rows.
// Identical math to the R3..R5 passing versions.
__global__ __launch_bounds__(512) void mlp_kernel(
    const float* __restrict__ attr, const float* __restrict__ W0,
    const float* __restrict__ b0, const float* __restrict__ W1,
    const float* __restrict__ b1, float* __restrict__ logits,
    float* __restrict__ f, uint4* __restrict__ zbase)
{
    const int t = threadIdx.x;
    const int b = blockIdx.x;
    // zero phase: consumed only by LATER kernels -> kernel-boundary safe (G16).
    {
        const int g = b * 512 + t;
        if (g < (int)(ZERO_BYTES / 16)) zbase[g] = make_uint4(0u, 0u, 0u, 0u);
    }

    __shared__ __align__(16) float attr_s[8 * DIM];   // 16 KB
    __shared__ __align__(16) float x_s[8 * HID];      // 8 KB
    const int node0 = b * 8;
    const float* ap = attr + (size_t)node0 * DIM;
    for (int i = t; i < 8 * DIM / 4; i += 512)
        ((float4*)attr_s)[i] = ((const float4*)ap)[i];
    __syncthreads();

    // hidden: 4 node-groups x 128 threads; thread = 2 hidden units x 2 nodes
    const int pg = t >> 7;
    const int hh = (t & 127) * 2;
    const float2 b0v = *(const float2*)(b0 + hh);
    float acc0[2], acc1[2];
#pragma unroll
    for (int n = 0; n < 2; n++) { acc0[n] = b0v.x; acc1[n] = b0v.y; }

    for (int k = 0; k < DIM; k += 4) {
        const float2 w0 = *(const float2*)(W0 + (k + 0) * HID + hh);
        const float2 w1 = *(const float2*)(W0 + (k + 1) * HID + hh);
        const float2 w2 = *(const float2*)(W0 + (k + 2) * HID + hh);
        const float2 w3 = *(const float2*)(W0 + (k + 3) * HID + hh);
#pragma unroll
        for (int n = 0; n < 2; n++) {
            const float4 a = *(const float4*)(attr_s + (2 * pg + n) * DIM + k);
            acc0[n] = fmaf(a.x, w0.x, acc0[n]); acc1[n] = fmaf(a.x, w0.y, acc1[n]);
            acc0[n] = fmaf(a.y, w1.x, acc0[n]); acc1[n] = fmaf(a.y, w1.y, acc1[n]);
            acc0[n] = fmaf(a.z, w2.x, acc0[n]); acc1[n] = fmaf(a.z, w2.y, acc1[n]);
            acc0[n] = fmaf(a.w, w3.x, acc0[n]); acc1[n] = fmaf(a.w, w3.y, acc1[n]);
        }
    }
#pragma unroll
    for (int n = 0; n < 2; n++) {
        x_s[(2 * pg + n) * HID + hh]     = fmaxf(acc0[n], 0.0f);
        x_s[(2 * pg + n) * HID + hh + 1] = fmaxf(acc1[n], 0.0f);
    }
    __syncthreads();

    if (t < 256) {
        const int n = t >> 5, c = t & 31;
        float lg = b1[c];
        for (int k = 0; k < HID; k += 4) {
            const float4 x4 = *(const float4*)(x_s + n * HID + k);
            lg = fmaf(x4.x, W1[(k + 0) * NCLS + c], lg);
            lg = fmaf(x4.y, W1[(k + 1) * NCLS + c], lg);
            lg = fmaf(x4.z, W1[(k + 2) * NCLS + c], lg);
            lg = fmaf(x4.w, W1[(k + 3) * NCLS + c], lg);
        }
        float sq = lg * lg;
#pragma unroll
        for (int m = 16; m >= 1; m >>= 1) sq += __shfl_xor(sq, m, 32);
        const float nr = fmaxf(sqrtf(sq), EPS_C);
        const int r = node0 + n;
        logits[r * NCLS + c] = lg;
        f[r * NCLS + c] = lg / nr;
    }
}

// ---------------- K2: edge sims + dedup -> raw ELL + raw COO overflow ----------
// col packed in low 12 mantissa bits of the fp32 sim (rel err 2^-12 -> ~1e-3 out).
__global__ __launch_bounds__(256) void edge_kernel(
    const int* __restrict__ row, const int* __restrict__ col,
    const float* __restrict__ f, unsigned int* __restrict__ bitmap,
    int* __restrict__ row_count, unsigned int* __restrict__ ell_raw,
    int2* __restrict__ ocoo, float* __restrict__ diag_sim,
    int* __restrict__ diag_ex, int* __restrict__ ocnt)
{
    const int e = blockIdx.x * blockDim.x + threadIdx.x;
    const int r = row[e], c = col[e];
    const float4* fr = (const float4*)(f + r * NCLS);
    const float4* fc = (const float4*)(f + c * NCLS);
    float sim = 0.f;
#pragma unroll
    for (int q = 0; q < 8; q++) {
        float4 a = fr[q], b = fc[q];
        sim += a.x * b.x + a.y * b.y + a.z * b.z + a.w * b.w;
    }
    if (sim < 0.1f) return;  // where(sim<0.1, 0, sim): zero == absent cell
    if (r == c) {
        diag_ex[r] = 1;                  // dup writes identical
        diag_sim[r] = sim;
    } else {
        // dedup: .at[r,c].set counts a cell ONCE even with duplicate edges
        unsigned int bit = (unsigned int)r * N_NODE + (unsigned int)c;
        unsigned int w = bit >> 5, m = 1u << (bit & 31);
        unsigned int old = atomicOr(&bitmap[w], m);
        if (!(old & m)) {
            int pos = atomicAdd(&row_count[r], 1);
            if (pos < ELLW) {
                unsigned int u = (__float_as_uint(sim) & ~0xFFFu) | (unsigned int)c;
                ell_raw[pos * N_NODE + r] = u;   // [slot][row]: lane-coalesced
            } else {
                int o = atomicAdd(ocnt, 1);
                ocoo[o] = make_int2((r << 12) | c, __float_as_int(sim));
            }
        }
    }
}

// ---------------- K3: block-local transform + register-ELL Jacobi solve -------
// Block cb owns column cb. Transform computed redundantly per block, entirely in
// registers/LDS (no same-kernel cross-block global write->read -- R4's bug).
// __launch_bounds__(1024, 4): 4 waves/SIMD -> 128-VGPR cap so ellreg[4][12]
// (48 regs) stays RESIDENT (R5's (1024) default capped at 64 -> scratch spill,
// 48 scratch reloads/thread/iter -> 4.8 ms). Sweeps via macro on explicit
// __shared__ arrays so every Y access is a provably-LDS ds_read.
__global__ __launch_bounds__(1024, 4) void solve_kernel(
    const float* __restrict__ logits, const unsigned int* __restrict__ ell_raw,
    const int2* __restrict__ ocoo, const int* __restrict__ cnt,
    const int* __restrict__ row_count, const int* __restrict__ diag_ex,
    const float* __restrict__ diag_sim, float* __restrict__ out)
{
    __shared__ float Ya[N_NODE];    // 16 KB Y (even)
    __shared__ float Yb[N_NODE];    // 16 KB Y (odd); prologue: overflow-exp acc
    __shared__ float tDen[N_NODE];  // 16 KB denom; prologue: ovf rowsum acc
    __shared__ float tInv[N_NODE];  // 16 KB ALPHA/degA (alpha folded for ovf use)
    // 64 KB total

    const int t  = threadIdx.x;
    const int cb = blockIdx.x;
    const int no = cnt[0];

    const float S00 = diag_ex[0] ? diag_sim[0] : 0.0f;
    const int rm  = (S00 == 1.0f) ? 1 : 0;                // remove diagonal?
    const int add = ((rm ? 0.0f : S00) == 0.0f) ? 1 : 0;  // add diag(lam)?

    // --- prologue A: zero scratch; raw overflow row-sum contributions ---
#pragma unroll
    for (int q = 0; q < 4; q++) { int r = t + q * 1024; tDen[r] = 0.0f; Yb[r] = 0.0f; }
    __syncthreads();
    for (int i = t; i < no; i += 1024) {
        int2 u = ocoo[i];
        atomicAdd(&tDen[u.x >> 12], __int_as_float(u.y));
    }
    __syncthreads();

    // --- prologue B: load ELL into registers; row sums -> denom (own cell only)
    unsigned int ellreg[4][ELLW];     // 48 VGPRs, live through all sweeps
#pragma unroll
    for (int q = 0; q < 4; q++) {
        const int r = t + q * 1024;
        float ssum = 0.0f;
#pragma unroll
        for (int s = 0; s < ELLW; s++) {
            unsigned int u = ell_raw[s * N_NODE + r];   // coalesced dword
            ellreg[q][s] = u;
            ssum += __uint_as_float(u & ~0xFFFu);       // padding u=0 adds 0
        }
        const float d = diag_ex[r] ? diag_sim[r] : 0.0f;
        const float d_eff = rm ? 0.0f : d;
        const float rowsum = d_eff + ssum + tDen[r];    // all vals >= 0.1 > 0
        tDen[r] = (rowsum == 0.0f) ? 1.0f : rowsum;     // own cell: no race
    }
    __syncthreads();

    // --- prologue C: overflow exp contributions (into Yb) ---
    for (int i = t; i < no; i += 1024) {
        int2 u = ocoo[i]; int r = u.x >> 12;
        atomicAdd(&Yb[r], expf(__int_as_float(u.y) / tDen[r]));
    }
    __syncthreads();

    // --- prologue D: degA, inv, pdiag; transform ELL in registers; init Y0 ---
    float base[4], pd[4];
#pragma unroll
    for (int q = 0; q < 4; q++) {
        const int r = t + q * 1024;
        const float denom = tDen[r];
        float esum = 0.0f;
#pragma unroll
        for (int s = 0; s < ELLW; s++) {
            unsigned int u = ellreg[q][s];
            float v = __uint_as_float(u & ~0xFFFu);
            esum += u ? expf(v / denom) : 0.0f;         // exp only on nz pattern
        }
        const float d = diag_ex[r] ? diag_sim[r] : 0.0f;
        const float d_eff = rm ? 0.0f : d;
        const float sn_d = d_eff / denom;
        const int degree = row_count[r] + ((sn_d != 0.0f) ? 1 : 0);
        const float lam = 1.0f / (float)(degree + 1);
        const float diagf = sn_d + (add ? lam : 0.0f);
        const float a_d = (diagf != 0.0f) ? expf(diagf) : 0.0f;
        const float degA = a_d + esum + Yb[r];
        const float inv = 1.0f / fmaxf(degA, EPS_C);
        tInv[r] = ALPHA_C * inv;                         // alpha folded for ovf
        pd[q] = ALPHA_C * a_d * inv;
#pragma unroll
        for (int s = 0; s < ELLW; s++) {
            unsigned int u = ellreg[q][s], outu = 0u;
            if (u) {
                float v = __uint_as_float(u & ~0xFFFu);
                float tv = ALPHA_C * expf(v / denom) * inv;
                outu = (__float_as_uint(tv) & ~0xFFFu) | (u & 0xFFFu);
            }
            ellreg[q][s] = outu;                         // stays in registers
        }
        base[q] = (1.0f - ALPHA_C) * logits[r * NCLS + cb];
        Ya[r] = base[q];                                 // Y0 = (1-a)L
    }
    __syncthreads();

    // --- 22 Jacobi sweeps (11 unrolled pairs), then Perron extrapolation ---
    // SRC/DST are literal __shared__ arrays -> ds_read guaranteed (no generic phi).
#define SWEEP(SRC, DST)                                                        \
    do {                                                                       \
        _Pragma("unroll")                                                      \
        for (int q = 0; q < 4; q++) {                                          \
            const int r = t + q * 1024;                                        \
            float acc = fmaf(pd[q], SRC[r], base[q]);                          \
            _Pragma("unroll")                                                  \
            for (int s = 0; s < ELLW; s++) {                                   \
                unsigned int u = ellreg[q][s];                                 \
                acc = fmaf(__uint_as_float(u & ~0xFFFu), SRC[u & 0xFFFu], acc);\
            }                                                                  \
            DST[r] = acc;                                                      \
        }                                                                      \
        __syncthreads();                                                       \
        for (int i = t; i < no; i += 1024) {                                   \
            int2 u = ocoo[i]; int rr = u.x >> 12;                              \
            float tv = expf(__int_as_float(u.y) / tDen[rr]) * tInv[rr];        \
            atomicAdd(&DST[rr], tv * SRC[u.x & 0xFFF]);                        \
        }                                                                      \
        __syncthreads();                                                       \
    } while (0)

    for (int ii = 0; ii < N_ITER / 2; ++ii) {   // Y_{2ii+2} lands in Ya
        SWEEP(Ya, Yb);
        SWEEP(Yb, Ya);
    }
#undef SWEEP

    // Perron mode (eigenvalue exactly ALPHA along all-ones, per component):
    // Y* = Y_K + (Y_K - Y_{K-1}) * a/(1-a); kills the 0.85-rate error mode.
#pragma unroll
    for (int q = 0; q < 4; q++) {
        const int r = t + q * 1024;
        const float yk = Ya[r], ykm1 = Yb[r];
        out[r * NCLS + cb] = yk + EXTRAP * (yk - ykm1);
    }
}

// ---------------- launch: 3 graph nodes ----------------
extern "C" void kernel_launch(void* const* d_in, const int* in_sizes, int n_in,
                              void* d_out, int out_size, void* d_ws, size_t ws_size,
                              hipStream_t stream)
{
    const float* attr = (const float*)d_in[0];
    const int*   row  = (const int*)d_in[1];
    const int*   col  = (const int*)d_in[2];
    const float* W0   = (const float*)d_in[3];
    const float* b0   = (const float*)d_in[4];
    const float* W1   = (const float*)d_in[5];
    const float* b1   = (const float*)d_in[6];
    float* out = (float*)d_out;

    char* ws = (char*)d_ws;
    unsigned int* bitmap  = (unsigned int*)(ws + OFF_BITMAP);
    unsigned int* ell_raw = (unsigned int*)(ws + OFF_ELLRAW);
    int*   row_count = (int*)(ws + OFF_ROWCNT);
    int*   diag_ex   = (int*)(ws + OFF_DIAGEX);
    int*   cnt       = (int*)(ws + OFF_CNT);
    float* logits    = (float*)(ws + OFF_LOGITS);
    float* f         = (float*)(ws + OFF_F);
    float* diag_sim  = (float*)(ws + OFF_DIAGSIM);
    int2*  ocoo      = (int2*)(ws + OFF_OCOO);

    mlp_kernel<<<N_NODE / 8, 512, 0, stream>>>(attr, W0, b0, W1, b1, logits, f,
                                               (uint4*)ws);
    edge_kernel<<<N_EDGE / 256, 256, 0, stream>>>(row, col, f, bitmap, row_count,
                                                  ell_raw, ocoo, diag_sim,
                                                  diag_ex, cnt);
    solve_kernel<<<NCLS, 1024, 0, stream>>>(logits, ell_raw, ocoo, cnt,
                                            row_count, diag_ex, diag_sim, out);
}